// Round 2
// baseline (52771.234 us; speedup 1.0000x reference)
//
#include <hip/hip_runtime.h>

#define TS   576
#define HID  128
#define GT   512     // 4*HID
#define K0   144     // 15 (x, emb-folded) + 128 (h0) + 1 pad
#define K1   256     // 128 (out0) + 128 (h1)
#define BB   4       // batch rows per block
#define NT   512     // threads per block (8 waves)

// static device scratch for prepped weights
#define WT0_OFF   0
#define B0_OFF    (K0*GT)            // 73728
#define WT1_OFF   (B0_OFF + GT)      // 74240
#define B1_OFF    (WT1_OFF + K1*GT)  // 205312
#define WS_FLOATS (B1_OFF + GT)      // 205824
__device__ float g_ws[WS_FLOATS];

__global__ void prep_kernel(const float* __restrict__ W_emb, const float* __restrict__ b_emb,
                            const float* __restrict__ W_ih0, const float* __restrict__ W_hh0,
                            const float* __restrict__ b_ih0, const float* __restrict__ b_hh0,
                            const float* __restrict__ W_ih1, const float* __restrict__ W_hh1,
                            const float* __restrict__ b_ih1, const float* __restrict__ b_hh1)
{
    const int j = blockIdx.x * blockDim.x + threadIdx.x;
    if (j >= GT) return;
    float* Wt0 = g_ws + WT0_OFF;
    float* b0  = g_ws + B0_OFF;
    float* Wt1 = g_ws + WT1_OFF;
    float* b1  = g_ws + B1_OFF;

    // fold embedding: Wcomb[j][i] = sum_c W_ih0[j][c] * W_emb[c][i]  (k-major store)
    for (int i = 0; i < 15; ++i) {
        float s = 0.f;
        for (int c = 0; c < 32; ++c) s = fmaf(W_ih0[j*32 + c], W_emb[c*15 + i], s);
        Wt0[i*GT + j] = s;
    }
    for (int k = 0; k < HID; ++k) Wt0[(15 + k)*GT + j] = W_hh0[j*HID + k];
    Wt0[143*GT + j] = 0.f;  // pad row
    float bb = b_ih0[j] + b_hh0[j];
    for (int c = 0; c < 32; ++c) bb = fmaf(W_ih0[j*32 + c], b_emb[c], bb);
    b0[j] = bb;

    for (int k = 0; k < HID; ++k) Wt1[k*GT + j]         = W_ih1[j*HID + k];
    for (int k = 0; k < HID; ++k) Wt1[(HID + k)*GT + j] = W_hh1[j*HID + k];
    b1[j] = b_ih1[j] + b_hh1[j];
}

__device__ __forceinline__ float sigm(float v) { return 1.f / (1.f + __expf(-v)); }

// a.{xyzw} += sv * w.{xyzw}
#define FMARC(a, sv, w) \
    a.x = fmaf(sv, w.x, a.x); a.y = fmaf(sv, w.y, a.y); \
    a.z = fmaf(sv, w.z, a.z); a.w = fmaf(sv, w.w, a.w);

// Register-resident-weight GEMM slice: this thread's 4 cols x its k-slice,
// all 4 batch rows. wv: NCH*4 float4 weight regs (k-major, 4 cols each).
// s*: per-row LDS source pointers at the k-slice base (uniform addr -> broadcast).
template<int NCH>
__device__ __forceinline__ void gemm_reg(const float4* __restrict__ wv,
                                         const float* __restrict__ s0,
                                         const float* __restrict__ s1,
                                         const float* __restrict__ s2,
                                         const float* __restrict__ s3,
                                         float4 binit, float* pp, int q4)
{
    float4 a0 = binit, a1 = binit, a2 = binit, a3 = binit;
    #pragma unroll
    for (int ch = 0; ch < NCH; ++ch) {
        const float4 v0 = *(const float4*)(s0 + 4*ch);
        const float4 v1 = *(const float4*)(s1 + 4*ch);
        const float4 v2 = *(const float4*)(s2 + 4*ch);
        const float4 v3 = *(const float4*)(s3 + 4*ch);
        float4 w;
        w = wv[4*ch + 0];
        FMARC(a0, v0.x, w) FMARC(a1, v1.x, w) FMARC(a2, v2.x, w) FMARC(a3, v3.x, w)
        w = wv[4*ch + 1];
        FMARC(a0, v0.y, w) FMARC(a1, v1.y, w) FMARC(a2, v2.y, w) FMARC(a3, v3.y, w)
        w = wv[4*ch + 2];
        FMARC(a0, v0.z, w) FMARC(a1, v1.z, w) FMARC(a2, v2.z, w) FMARC(a3, v3.z, w)
        w = wv[4*ch + 3];
        FMARC(a0, v0.w, w) FMARC(a1, v1.w, w) FMARC(a2, v2.w, w) FMARC(a3, v3.w, w)
    }
    *(float4*)(pp + 0*GT + q4) = a0;
    *(float4*)(pp + 1*GT + q4) = a1;
    *(float4*)(pp + 2*GT + q4) = a2;
    *(float4*)(pp + 3*GT + q4) = a3;
}

__global__ __launch_bounds__(NT, 1) void lstm_main(
    const float* __restrict__ x,
    const float* __restrict__ W_fc1, const float* __restrict__ b_fc1,
    const float* __restrict__ W_fc2, const float* __restrict__ b_fc2,
    float* __restrict__ out)
{
    __shared__ float src0[BB][K0];       // [15 x-cols | 128 h0 | pad]
    __shared__ float src1[BB][K1];       // [128 out0 | 128 h1]
    __shared__ float part[4][BB][GT];    // k-split partial sums (32 KB)

    const float* Wt0 = g_ws + WT0_OFF;
    const float* bs0 = g_ws + B0_OFF;
    const float* Wt1 = g_ws + WT1_OFF;
    const float* bs1 = g_ws + B1_OFF;

    const int tid  = threadIdx.x;
    const int cg   = tid & 127;           // colgroup 0..127
    const int q4   = cg << 2;             // col quad base
    const int ks   = tid >> 7;            // k-split 0..3 (wave-uniform)
    const int um   = tid & 127;           // update: unit
    const int ur   = tid >> 7;            // update: row 0..3
    const int row0 = blockIdx.x * BB;

    const int k0b = ks * 36;   // L0 k-range [k0b, k0b+36)
    const int k1b = ks * 64;   // L1 k-range [k1b, k1b+64)

    // ---- load this thread's persistent weight tile into registers ----
    float4 w0v[36];
    float4 w1v[64];
    {
        const float* p0 = Wt0 + (size_t)k0b * GT + q4;
        #pragma unroll
        for (int k = 0; k < 36; ++k) w0v[k] = *(const float4*)(p0 + (size_t)k * GT);
        const float* p1 = Wt1 + (size_t)k1b * GT + q4;
        #pragma unroll
        for (int k = 0; k < 64; ++k) w1v[k] = *(const float4*)(p1 + (size_t)k * GT);
    }
    const float4 bq0 = *(const float4*)(bs0 + q4);
    const float4 bq1 = *(const float4*)(bs1 + q4);
    const float4 zz  = make_float4(0.f, 0.f, 0.f, 0.f);
    const float4 i0  = (ks == 0) ? bq0 : zz;   // bias folded into ks==0 partial
    const float4 i1  = (ks == 0) ? bq1 : zz;
    float c0 = 0.f, c1 = 0.f;

    for (int i = tid; i < BB*K0; i += NT) (&src0[0][0])[i] = 0.f;
    for (int i = tid; i < BB*K1; i += NT) (&src1[0][0])[i] = 0.f;

    // x loader role (threads 0..59 load 4 rows x 15 features)
    const int lr = tid / 15, li = tid - lr * 15;
    const float* xp = x + (size_t)(row0 + (tid < 60 ? lr : 0)) * (TS * 15) + (tid < 60 ? li : 0);

    __syncthreads();
    if (tid < 60) src0[lr][li] = xp[0];
    __syncthreads();

    float* pbase = &part[ks][0][0];

    for (int t = 0; t < TS; ++t) {
        // ---- L0 GEMM: gates += [x|h0] @ Wt0 (weights in regs) ----
        gemm_reg<9>(w0v,
                    &src0[0][k0b], &src0[1][k0b], &src0[2][k0b], &src0[3][k0b],
                    i0, pbase, q4);
        __syncthreads();
        // ---- L0 cell update ----
        {
            float gi = part[0][ur][um]        + part[1][ur][um]        + part[2][ur][um]        + part[3][ur][um];
            float gf = part[0][ur][128 + um]  + part[1][ur][128 + um]  + part[2][ur][128 + um]  + part[3][ur][128 + um];
            float gg = part[0][ur][256 + um]  + part[1][ur][256 + um]  + part[2][ur][256 + um]  + part[3][ur][256 + um];
            float go = part[0][ur][384 + um]  + part[1][ur][384 + um]  + part[2][ur][384 + um]  + part[3][ur][384 + um];
            float iv = sigm(gi), fv = sigm(gf), ov = sigm(go);
            float gv = tanhf(gg);
            c0 = fmaf(fv, c0, iv * gv);
            float hv = ov * tanhf(c0);
            src0[ur][15 + um] = hv;   // h0 for next step's L0 GEMM
            src1[ur][um]      = hv;   // out0[t] feeding L1
        }
        __syncthreads();
        // ---- L1 GEMM (+ prefetch next x slab into src0[:, 0:15]) ----
        if (t + 1 < TS && tid < 60) src0[lr][li] = xp[(size_t)(t + 1) * 15];
        gemm_reg<16>(w1v,
                     &src1[0][k1b], &src1[1][k1b], &src1[2][k1b], &src1[3][k1b],
                     i1, pbase, q4);
        __syncthreads();
        // ---- L1 cell update ----
        {
            float gi = part[0][ur][um]        + part[1][ur][um]        + part[2][ur][um]        + part[3][ur][um];
            float gf = part[0][ur][128 + um]  + part[1][ur][128 + um]  + part[2][ur][128 + um]  + part[3][ur][128 + um];
            float gg = part[0][ur][256 + um]  + part[1][ur][256 + um]  + part[2][ur][256 + um]  + part[3][ur][256 + um];
            float go = part[0][ur][384 + um]  + part[1][ur][384 + um]  + part[2][ur][384 + um]  + part[3][ur][384 + um];
            float iv = sigm(gi), fv = sigm(gf), ov = sigm(go);
            float gv = tanhf(gg);
            c1 = fmaf(fv, c1, iv * gv);
            float hv = ov * tanhf(c1);
            src1[ur][128 + um] = hv;  // h1
        }
        __syncthreads();
    }

    // ---- FC head: relu(h1 @ W_fc1^T + b_fc1) @ W_fc2^T + b_fc2 ----
    if (tid < BB * 64) {
        const int rr = tid >> 6, u = tid & 63;
        float acc = b_fc1[u];
        #pragma unroll 8
        for (int k = 0; k < HID; ++k) acc = fmaf(src1[rr][HID + k], W_fc1[u*HID + k], acc);
        part[0][rr][u] = fmaxf(acc, 0.f);
    }
    __syncthreads();
    if (tid < BB) {
        float acc = b_fc2[0];
        #pragma unroll 8
        for (int u = 0; u < 64; ++u) acc = fmaf(part[0][tid][u], W_fc2[u], acc);
        out[row0 + tid] = acc;
    }
}

extern "C" void kernel_launch(void* const* d_in, const int* in_sizes, int n_in,
                              void* d_out, int out_size, void* d_ws, size_t ws_size,
                              hipStream_t stream)
{
    const float* x     = (const float*)d_in[0];
    const float* W_emb = (const float*)d_in[1];
    const float* b_emb = (const float*)d_in[2];
    const float* W_ih0 = (const float*)d_in[3];
    const float* W_hh0 = (const float*)d_in[4];
    const float* b_ih0 = (const float*)d_in[5];
    const float* b_hh0 = (const float*)d_in[6];
    const float* W_ih1 = (const float*)d_in[7];
    const float* W_hh1 = (const float*)d_in[8];
    const float* b_ih1 = (const float*)d_in[9];
    const float* b_hh1 = (const float*)d_in[10];
    const float* W_fc1 = (const float*)d_in[11];
    const float* b_fc1 = (const float*)d_in[12];
    const float* W_fc2 = (const float*)d_in[13];
    const float* b_fc2 = (const float*)d_in[14];
    float* out = (float*)d_out;

    prep_kernel<<<2, 256, 0, stream>>>(W_emb, b_emb, W_ih0, W_hh0, b_ih0, b_hh0,
                                       W_ih1, W_hh1, b_ih1, b_hh1);
    lstm_main<<<2048 / BB, NT, 0, stream>>>(x, W_fc1, b_fc1, W_fc2, b_fc2, out);
}

// Round 4
// 38942.096 us; speedup vs baseline: 1.3551x; 1.3551x over previous
//
#include <hip/hip_runtime.h>

#define TS   576
#define HID  128
#define GT   512     // 4*HID
#define K0P  160     // 15 x (emb-folded) + 128 h0 + 17 zero-pad (float4-aligned 8-way k-split)
#define K1   256     // 128 out0 + 128 h1
#define BB   8       // batch rows per block
#define NT   1024    // threads per block (16 waves)

// static device scratch for prepped weights
#define WT0_OFF   0
#define B0_OFF    (K0P*GT)             // 81920
#define WT1_OFF   (B0_OFF + GT)        // 82432
#define B1_OFF    (WT1_OFF + K1*GT)    // 213504
#define WS_FLOATS (B1_OFF + GT)        // 214016
__device__ float g_ws[WS_FLOATS];

// Column permutation: original gate row jo (g*128+u, PyTorch order i,f,g,o)
// is stored at column jn = u*4 + g, so a float4 of consecutive columns holds
// all 4 gates of one hidden unit.
__global__ void prep_kernel(const float* __restrict__ W_emb, const float* __restrict__ b_emb,
                            const float* __restrict__ W_ih0, const float* __restrict__ W_hh0,
                            const float* __restrict__ b_ih0, const float* __restrict__ b_hh0,
                            const float* __restrict__ W_ih1, const float* __restrict__ W_hh1,
                            const float* __restrict__ b_ih1, const float* __restrict__ b_hh1)
{
    const int jo = blockIdx.x * blockDim.x + threadIdx.x;
    if (jo >= GT) return;
    const int g  = jo >> 7;         // gate 0..3 (i,f,g,o)
    const int u  = jo & 127;        // unit
    const int jn = (u << 2) | g;    // interleaved column

    float* Wt0 = g_ws + WT0_OFF;
    float* b0  = g_ws + B0_OFF;
    float* Wt1 = g_ws + WT1_OFF;
    float* b1  = g_ws + B1_OFF;

    // fold embedding: Wcomb[jo][i] = sum_c W_ih0[jo][c] * W_emb[c][i]
    for (int i = 0; i < 15; ++i) {
        float s = 0.f;
        for (int c = 0; c < 32; ++c) s = fmaf(W_ih0[jo*32 + c], W_emb[c*15 + i], s);
        Wt0[i*GT + jn] = s;
    }
    for (int k = 0; k < HID; ++k) Wt0[(15 + k)*GT + jn] = W_hh0[jo*HID + k];
    for (int k = 143; k < K0P; ++k) Wt0[k*GT + jn] = 0.f;   // zero pad rows
    float bb = b_ih0[jo] + b_hh0[jo];
    for (int c = 0; c < 32; ++c) bb = fmaf(W_ih0[jo*32 + c], b_emb[c], bb);
    b0[jn] = bb;

    for (int k = 0; k < HID; ++k) Wt1[k*GT + jn]         = W_ih1[jo*HID + k];
    for (int k = 0; k < HID; ++k) Wt1[(HID + k)*GT + jn] = W_hh1[jo*HID + k];
    b1[jn] = b_ih1[jo] + b_hh1[jo];
}

__device__ __forceinline__ float sigm(float v) { return 1.f / (1.f + __expf(-v)); }

// NOTE: macro params must not collide with .x/.y/.z/.w member tokens.
#define FMARC(A_, SV_, W_) \
    A_.x = fmaf(SV_, W_.x, A_.x); A_.y = fmaf(SV_, W_.y, A_.y); \
    A_.z = fmaf(SV_, W_.z, A_.z); A_.w = fmaf(SV_, W_.w, A_.w);

__global__ __launch_bounds__(NT, 1) void lstm_main(
    const float* __restrict__ x,
    const float* __restrict__ W_fc1, const float* __restrict__ b_fc1,
    const float* __restrict__ W_fc2, const float* __restrict__ b_fc2,
    float* __restrict__ out)
{
    __shared__ float src0[BB][K0P];     // [15 x | 128 h0 | 17 pad]   5 KB
    __shared__ float src1[BB][K1];      // [128 out0 | 128 h1]        8 KB
    __shared__ float part[8][BB][GT];   // 8-way k-split partials   128 KB

    const int tid  = threadIdx.x;
    const int cg   = tid & 127;          // colgroup (unit) 0..127
    const int q4   = cg << 2;            // column quad base
    const int ks   = tid >> 7;           // k-split 0..7 (wave-uniform)
    const int um   = tid & 127;          // update: unit
    const int ur   = tid >> 7;           // update: row 0..7
    const int row0 = blockIdx.x * BB;
    const int k0b  = ks * 20;            // L0 k-slice base
    const int k1b  = ks * 32;            // L1 k-slice base

    const float* Wt0 = g_ws + WT0_OFF;
    const float* bs0 = g_ws + B0_OFF;
    const float* Wt1 = g_ws + WT1_OFF;
    const float* bs1 = g_ws + B1_OFF;

    // ---- persistent weights in NAMED registers (no arrays -> no demotion) ----
    const float* p0 = Wt0 + (size_t)k0b * GT + q4;
    const float* p1 = Wt1 + (size_t)k1b * GT + q4;
#define DECLA(i) const float4 wa##i = *(const float4*)(p0 + (i)*GT);
    DECLA(0)  DECLA(1)  DECLA(2)  DECLA(3)  DECLA(4)
    DECLA(5)  DECLA(6)  DECLA(7)  DECLA(8)  DECLA(9)
    DECLA(10) DECLA(11) DECLA(12) DECLA(13) DECLA(14)
    DECLA(15) DECLA(16) DECLA(17) DECLA(18) DECLA(19)
#define DECLB(i) const float4 wb##i = *(const float4*)(p1 + (i)*GT);
    DECLB(0)  DECLB(1)  DECLB(2)  DECLB(3)  DECLB(4)  DECLB(5)  DECLB(6)  DECLB(7)
    DECLB(8)  DECLB(9)  DECLB(10) DECLB(11) DECLB(12) DECLB(13) DECLB(14) DECLB(15)
    DECLB(16) DECLB(17) DECLB(18) DECLB(19) DECLB(20) DECLB(21) DECLB(22) DECLB(23)
    DECLB(24) DECLB(25) DECLB(26) DECLB(27) DECLB(28) DECLB(29) DECLB(30) DECLB(31)

    const float4 zz = make_float4(0.f, 0.f, 0.f, 0.f);
    const float4 i0 = (ks == 0) ? *(const float4*)(bs0 + q4) : zz;  // bias in ks==0 partial
    const float4 i1 = (ks == 0) ? *(const float4*)(bs1 + q4) : zz;
    float c0 = 0.f, c1 = 0.f;

    for (int i = tid; i < BB*K0P; i += NT) (&src0[0][0])[i] = 0.f;
    for (int i = tid; i < BB*K1;  i += NT) (&src1[0][0])[i] = 0.f;

    // x loader role: threads 0..119 load 8 rows x 15 features
    const int lr = tid / 15, li = tid - lr * 15;
    const float* xp = x + (size_t)(row0 + (tid < 120 ? lr : 0)) * (TS * 15) + (tid < 120 ? li : 0);

    __syncthreads();
    if (tid < 120) src0[lr][li] = xp[0];
    __syncthreads();

    float* pp = &part[ks][0][0];

// L0: this thread's 4 cols x 20-k slice, one batch row. Sources are wave-uniform (broadcast).
#define L0_ROW(r) { \
    const float4* sp = (const float4*)(&src0[r][0] + k0b); \
    const float4 s0 = sp[0], s1 = sp[1], s2 = sp[2], s3 = sp[3], s4 = sp[4]; \
    float4 acc = i0; \
    FMARC(acc, s0.x, wa0)  FMARC(acc, s0.y, wa1)  FMARC(acc, s0.z, wa2)  FMARC(acc, s0.w, wa3)  \
    FMARC(acc, s1.x, wa4)  FMARC(acc, s1.y, wa5)  FMARC(acc, s1.z, wa6)  FMARC(acc, s1.w, wa7)  \
    FMARC(acc, s2.x, wa8)  FMARC(acc, s2.y, wa9)  FMARC(acc, s2.z, wa10) FMARC(acc, s2.w, wa11) \
    FMARC(acc, s3.x, wa12) FMARC(acc, s3.y, wa13) FMARC(acc, s3.z, wa14) FMARC(acc, s3.w, wa15) \
    FMARC(acc, s4.x, wa16) FMARC(acc, s4.y, wa17) FMARC(acc, s4.z, wa18) FMARC(acc, s4.w, wa19) \
    *(float4*)(pp + (r)*GT + q4) = acc; }

#define L1_ROW(r) { \
    const float4* sp = (const float4*)(&src1[r][0] + k1b); \
    const float4 s0 = sp[0], s1 = sp[1], s2 = sp[2], s3 = sp[3]; \
    const float4 s4 = sp[4], s5 = sp[5], s6 = sp[6], s7 = sp[7]; \
    float4 acc = i1; \
    FMARC(acc, s0.x, wb0)  FMARC(acc, s0.y, wb1)  FMARC(acc, s0.z, wb2)  FMARC(acc, s0.w, wb3)  \
    FMARC(acc, s1.x, wb4)  FMARC(acc, s1.y, wb5)  FMARC(acc, s1.z, wb6)  FMARC(acc, s1.w, wb7)  \
    FMARC(acc, s2.x, wb8)  FMARC(acc, s2.y, wb9)  FMARC(acc, s2.z, wb10) FMARC(acc, s2.w, wb11) \
    FMARC(acc, s3.x, wb12) FMARC(acc, s3.y, wb13) FMARC(acc, s3.z, wb14) FMARC(acc, s3.w, wb15) \
    FMARC(acc, s4.x, wb16) FMARC(acc, s4.y, wb17) FMARC(acc, s4.z, wb18) FMARC(acc, s4.w, wb19) \
    FMARC(acc, s5.x, wb20) FMARC(acc, s5.y, wb21) FMARC(acc, s5.z, wb22) FMARC(acc, s5.w, wb23) \
    FMARC(acc, s6.x, wb24) FMARC(acc, s6.y, wb25) FMARC(acc, s6.z, wb26) FMARC(acc, s6.w, wb27) \
    FMARC(acc, s7.x, wb28) FMARC(acc, s7.y, wb29) FMARC(acc, s7.z, wb30) FMARC(acc, s7.w, wb31) \
    *(float4*)(pp + (r)*GT + q4) = acc; }

    #pragma unroll 1
    for (int t = 0; t < TS; ++t) {
        // ---- L0 GEMM: gates = [x|h0] @ Wt0 (weights in regs) ----
        L0_ROW(0) L0_ROW(1) L0_ROW(2) L0_ROW(3)
        L0_ROW(4) L0_ROW(5) L0_ROW(6) L0_ROW(7)
        __syncthreads();
        // ---- L0 cell update (gate-interleaved: float4 = i,f,g,o of unit um) ----
        {
            const int ub = um << 2;
            float4 gv = *(const float4*)(&part[0][ur][ub]);
            #pragma unroll
            for (int s = 1; s < 8; ++s) {
                const float4 p = *(const float4*)(&part[s][ur][ub]);
                gv.x += p.x; gv.y += p.y; gv.z += p.z; gv.w += p.w;
            }
            const float iv = sigm(gv.x), fv = sigm(gv.y), ov = sigm(gv.w);
            const float gg = tanhf(gv.z);
            c0 = fmaf(fv, c0, iv * gg);
            const float hv = ov * tanhf(c0);
            src0[ur][15 + um] = hv;   // h0 for next step
            src1[ur][um]      = hv;   // out0[t] feeding L1
        }
        __syncthreads();
        // ---- L1 GEMM (+ prefetch next x slab into src0[:, 0:15]) ----
        if (t + 1 < TS && tid < 120) src0[lr][li] = xp[(size_t)(t + 1) * 15];
        L1_ROW(0) L1_ROW(1) L1_ROW(2) L1_ROW(3)
        L1_ROW(4) L1_ROW(5) L1_ROW(6) L1_ROW(7)
        __syncthreads();
        // ---- L1 cell update ----
        {
            const int ub = um << 2;
            float4 gv = *(const float4*)(&part[0][ur][ub]);
            #pragma unroll
            for (int s = 1; s < 8; ++s) {
                const float4 p = *(const float4*)(&part[s][ur][ub]);
                gv.x += p.x; gv.y += p.y; gv.z += p.z; gv.w += p.w;
            }
            const float iv = sigm(gv.x), fv = sigm(gv.y), ov = sigm(gv.w);
            const float gg = tanhf(gv.z);
            c1 = fmaf(fv, c1, iv * gg);
            const float hv = ov * tanhf(c1);
            src1[ur][128 + um] = hv;  // h1
        }
        __syncthreads();
    }

    // ---- FC head: relu(h1 @ W_fc1^T + b_fc1) @ W_fc2^T + b_fc2 ----
    if (tid < BB * 64) {
        const int rr = tid >> 6, u = tid & 63;
        float acc = b_fc1[u];
        #pragma unroll 8
        for (int k = 0; k < HID; ++k) acc = fmaf(src1[rr][HID + k], W_fc1[u*HID + k], acc);
        part[0][rr][u] = fmaxf(acc, 0.f);
    }
    __syncthreads();
    if (tid < BB) {
        float acc = b_fc2[0];
        #pragma unroll 8
        for (int u = 0; u < 64; ++u) acc = fmaf(part[0][tid][u], W_fc2[u], acc);
        out[row0 + tid] = acc;
    }
}

extern "C" void kernel_launch(void* const* d_in, const int* in_sizes, int n_in,
                              void* d_out, int out_size, void* d_ws, size_t ws_size,
                              hipStream_t stream)
{
    const float* x     = (const float*)d_in[0];
    const float* W_emb = (const float*)d_in[1];
    const float* b_emb = (const float*)d_in[2];
    const float* W_ih0 = (const float*)d_in[3];
    const float* W_hh0 = (const float*)d_in[4];
    const float* b_ih0 = (const float*)d_in[5];
    const float* b_hh0 = (const float*)d_in[6];
    const float* W_ih1 = (const float*)d_in[7];
    const float* W_hh1 = (const float*)d_in[8];
    const float* b_ih1 = (const float*)d_in[9];
    const float* b_hh1 = (const float*)d_in[10];
    const float* W_fc1 = (const float*)d_in[11];
    const float* b_fc1 = (const float*)d_in[12];
    const float* W_fc2 = (const float*)d_in[13];
    const float* b_fc2 = (const float*)d_in[14];
    float* out = (float*)d_out;

    prep_kernel<<<2, 256, 0, stream>>>(W_emb, b_emb, W_ih0, W_hh0, b_ih0, b_hh0,
                                       W_ih1, W_hh1, b_ih1, b_hh1);
    lstm_main<<<2048 / BB, NT, 0, stream>>>(x, W_fc1, b_fc1, W_fc2, b_fc2, out);
}

// Round 5
// 10790.346 us; speedup vs baseline: 4.8906x; 3.6090x over previous
//
#include <hip/hip_runtime.h>

#define TS    576
#define HID   128
#define GT    512       // 4*HID
#define K0    144       // 15 x (emb-folded) | 128 h0 | 1 zero pad
#define BB    8         // batch rows per block
#define NT    512       // 8 waves -> 2 waves/SIMD -> 256 VGPR cap
#define TS128 (TS*HID)  // 73728

// prepped weights (k-major, gate-interleaved columns jn = unit*4 + gate)
__device__ float g_wt0[K0 * GT];     // [k][col]: k 0..14 x-proj (emb folded), 15..142 h, 143 zero
__device__ float g_b0[GT];
__device__ float g_wih1[HID * GT];   // [k][col]
__device__ float g_whh1[HID * GT];   // [k][col]
__device__ float g_b1[GT];
__device__ float g_out0[2048 * TS * HID];   // 604 MB intermediate: out0[b][t][128]

__global__ void prep_kernel(const float* __restrict__ W_emb, const float* __restrict__ b_emb,
                            const float* __restrict__ W_ih0, const float* __restrict__ W_hh0,
                            const float* __restrict__ b_ih0, const float* __restrict__ b_hh0,
                            const float* __restrict__ W_ih1, const float* __restrict__ W_hh1,
                            const float* __restrict__ b_ih1, const float* __restrict__ b_hh1)
{
    const int jo = blockIdx.x * blockDim.x + threadIdx.x;
    if (jo >= GT) return;
    const int g  = jo >> 7;         // gate 0..3 (i,f,g,o)
    const int u  = jo & 127;        // unit
    const int jn = (u << 2) | g;    // interleaved column

    // L0: fold embedding into x-projection
    for (int i = 0; i < 15; ++i) {
        float s = 0.f;
        for (int c = 0; c < 32; ++c) s = fmaf(W_ih0[jo*32 + c], W_emb[c*15 + i], s);
        g_wt0[i*GT + jn] = s;
    }
    for (int k = 0; k < HID; ++k) g_wt0[(15 + k)*GT + jn] = W_hh0[jo*HID + k];
    g_wt0[143*GT + jn] = 0.f;
    float bb = b_ih0[jo] + b_hh0[jo];
    for (int c = 0; c < 32; ++c) bb = fmaf(W_ih0[jo*32 + c], b_emb[c], bb);
    g_b0[jn] = bb;

    for (int k = 0; k < HID; ++k) g_wih1[k*GT + jn] = W_ih1[jo*HID + k];
    for (int k = 0; k < HID; ++k) g_whh1[k*GT + jn] = W_hh1[jo*HID + k];
    g_b1[jn] = b_ih1[jo] + b_hh1[jo];
}

__device__ __forceinline__ float sigm(float v) { return 1.f / (1.f + __expf(-v)); }

#define LD4(P_) (*(const float4*)(P_))
// macro params must never be named x/y/z/w/a/s
#define FMARC(A_, SV_, W_) \
    A_.x = fmaf(SV_, W_.x, A_.x); A_.y = fmaf(SV_, W_.y, A_.y); \
    A_.z = fmaf(SV_, W_.z, A_.z); A_.w = fmaf(SV_, W_.w, A_.w);

// ============================ Kernel A: layer-0 ============================
__global__ __launch_bounds__(NT, 2) void lstm_l0(
    const float* __restrict__ x, float* __restrict__ out0)
{
    __shared__ float src0[BB][K0];      // [15 x | 128 h0 | 1 pad]
    __shared__ float part[4][BB][GT];   // 4-way k-split partials (64 KB)

    const int tid  = threadIdx.x;
    const int cg   = tid & 127;
    const int q4   = cg << 2;
    const int ks   = tid >> 7;          // 0..3, wave-uniform
    const int um   = cg;                // update unit
    const int rlo  = tid >> 7;          // update rows rlo and rlo+4
    const int row0 = blockIdx.x * BB;
    const int k0b  = ks * 36;

    // persistent weights: 36 named float4 (144 VGPRs)
    const float* p0 = g_wt0 + (size_t)k0b * GT + q4;
#define DECLA(I_) const float4 wa##I_ = LD4(p0 + (I_)*GT);
    DECLA(0)  DECLA(1)  DECLA(2)  DECLA(3)  DECLA(4)  DECLA(5)
    DECLA(6)  DECLA(7)  DECLA(8)  DECLA(9)  DECLA(10) DECLA(11)
    DECLA(12) DECLA(13) DECLA(14) DECLA(15) DECLA(16) DECLA(17)
    DECLA(18) DECLA(19) DECLA(20) DECLA(21) DECLA(22) DECLA(23)
    DECLA(24) DECLA(25) DECLA(26) DECLA(27) DECLA(28) DECLA(29)
    DECLA(30) DECLA(31) DECLA(32) DECLA(33) DECLA(34) DECLA(35)

    const float4 zz = make_float4(0.f, 0.f, 0.f, 0.f);
    const float4 i0 = (ks == 0) ? LD4(g_b0 + q4) : zz;
    float c_a = 0.f, c_b = 0.f;

    for (int i = tid; i < BB*K0; i += NT) (&src0[0][0])[i] = 0.f;

    const int lr = tid / 15, li = tid - lr * 15;
    const float* xp = x + (size_t)(row0 + (tid < 120 ? lr : 0)) * (TS * 15) + (tid < 120 ? li : 0);

    __syncthreads();
    if (tid < 120) src0[lr][li] = xp[0];
    __syncthreads();

    float* pp = &part[ks][0][0];

#define L0R(R_) { \
    const float* sp_ = &src0[R_][k0b]; \
    const float4 s0_ = LD4(sp_+0),  s1_ = LD4(sp_+4),  s2_ = LD4(sp_+8); \
    const float4 s3_ = LD4(sp_+12), s4_ = LD4(sp_+16), s5_ = LD4(sp_+20); \
    const float4 s6_ = LD4(sp_+24), s7_ = LD4(sp_+28), s8_ = LD4(sp_+32); \
    float4 acc_ = i0; \
    FMARC(acc_, s0_.x, wa0)  FMARC(acc_, s0_.y, wa1)  FMARC(acc_, s0_.z, wa2)  FMARC(acc_, s0_.w, wa3)  \
    FMARC(acc_, s1_.x, wa4)  FMARC(acc_, s1_.y, wa5)  FMARC(acc_, s1_.z, wa6)  FMARC(acc_, s1_.w, wa7)  \
    FMARC(acc_, s2_.x, wa8)  FMARC(acc_, s2_.y, wa9)  FMARC(acc_, s2_.z, wa10) FMARC(acc_, s2_.w, wa11) \
    FMARC(acc_, s3_.x, wa12) FMARC(acc_, s3_.y, wa13) FMARC(acc_, s3_.z, wa14) FMARC(acc_, s3_.w, wa15) \
    FMARC(acc_, s4_.x, wa16) FMARC(acc_, s4_.y, wa17) FMARC(acc_, s4_.z, wa18) FMARC(acc_, s4_.w, wa19) \
    FMARC(acc_, s5_.x, wa20) FMARC(acc_, s5_.y, wa21) FMARC(acc_, s5_.z, wa22) FMARC(acc_, s5_.w, wa23) \
    FMARC(acc_, s6_.x, wa24) FMARC(acc_, s6_.y, wa25) FMARC(acc_, s6_.z, wa26) FMARC(acc_, s6_.w, wa27) \
    FMARC(acc_, s7_.x, wa28) FMARC(acc_, s7_.y, wa29) FMARC(acc_, s7_.z, wa30) FMARC(acc_, s7_.w, wa31) \
    FMARC(acc_, s8_.x, wa32) FMARC(acc_, s8_.y, wa33) FMARC(acc_, s8_.z, wa34) FMARC(acc_, s8_.w, wa35) \
    *(float4*)(pp + (R_)*GT + q4) = acc_; }

#define UPD0(R_, C_) { \
    const int ub_ = um << 2; \
    float4 gv_ = LD4(&part[0][R_][ub_]); \
    { const float4 p1_ = LD4(&part[1][R_][ub_]); gv_.x += p1_.x; gv_.y += p1_.y; gv_.z += p1_.z; gv_.w += p1_.w; } \
    { const float4 p2_ = LD4(&part[2][R_][ub_]); gv_.x += p2_.x; gv_.y += p2_.y; gv_.z += p2_.z; gv_.w += p2_.w; } \
    { const float4 p3_ = LD4(&part[3][R_][ub_]); gv_.x += p3_.x; gv_.y += p3_.y; gv_.z += p3_.z; gv_.w += p3_.w; } \
    const float iv_ = sigm(gv_.x), fv_ = sigm(gv_.y), ov_ = sigm(gv_.w); \
    const float gg_ = tanhf(gv_.z); \
    C_ = fmaf(fv_, C_, iv_ * gg_); \
    const float hv_ = ov_ * tanhf(C_); \
    src0[R_][15 + um] = hv_; \
    out0[(size_t)(row0 + (R_)) * TS128 + (size_t)t * HID + um] = hv_; }

    #pragma unroll 1
    for (int t = 0; t < TS; ++t) {
        float xnext = 0.f;
        if (tid < 120 && t + 1 < TS) xnext = xp[(size_t)(t + 1) * 15];
        L0R(0) L0R(1) L0R(2) L0R(3) L0R(4) L0R(5) L0R(6) L0R(7)
        __syncthreads();
        UPD0(rlo, c_a)
        { const int rhi_ = rlo + 4; UPD0(rhi_, c_b) }
        if (tid < 120 && t + 1 < TS) src0[lr][li] = xnext;
        __syncthreads();
    }
}

// ============================ Kernel C: layer-1 + FC head ============================
__global__ __launch_bounds__(NT, 2) void lstm_l1(
    const float* __restrict__ out0,
    const float* __restrict__ W_fc1, const float* __restrict__ b_fc1,
    const float* __restrict__ W_fc2, const float* __restrict__ b_fc2,
    float* __restrict__ out)
{
    __shared__ float h1s[BB][HID];       // h1 state              4 KB
    __shared__ float obuf[2][BB][HID];   // out0[t] double buffer 8 KB
    __shared__ float part[4][BB][GT];    // k-split partials     64 KB

    const int tid  = threadIdx.x;
    const int cg   = tid & 127;
    const int q4   = cg << 2;
    const int ks   = tid >> 7;
    const int um   = cg;
    const int rlo  = tid >> 7;
    const int row0 = blockIdx.x * BB;
    const int k1b  = ks * 32;

    // persistent W_hh1 slice: 32 named float4 (128 VGPRs)
    const float* ph = g_whh1 + (size_t)k1b * GT + q4;
#define DECLB(I_) const float4 wb##I_ = LD4(ph + (I_)*GT);
    DECLB(0)  DECLB(1)  DECLB(2)  DECLB(3)  DECLB(4)  DECLB(5)  DECLB(6)  DECLB(7)
    DECLB(8)  DECLB(9)  DECLB(10) DECLB(11) DECLB(12) DECLB(13) DECLB(14) DECLB(15)
    DECLB(16) DECLB(17) DECLB(18) DECLB(19) DECLB(20) DECLB(21) DECLB(22) DECLB(23)
    DECLB(24) DECLB(25) DECLB(26) DECLB(27) DECLB(28) DECLB(29) DECLB(30) DECLB(31)

    const float* pih = g_wih1 + (size_t)k1b * GT + q4;   // streamed per step (L2-resident)

    const float4 zz = make_float4(0.f, 0.f, 0.f, 0.f);
    const float4 i1 = (ks == 0) ? LD4(g_b1 + q4) : zz;
    float c_a = 0.f, c_b = 0.f;

    for (int i = tid; i < BB*HID; i += NT) (&h1s[0][0])[i] = 0.f;

    const int pr = tid >> 5, pk4 = (tid & 31) << 2;   // prefetch role (tid<256)
    float4 pf = zz;
    if (tid < 256) pf = LD4(out0 + (size_t)(row0 + pr) * TS128 + pk4);
    __syncthreads();
    if (tid < 256) *(float4*)(&obuf[0][pr][pk4]) = pf;
    __syncthreads();

    float* pp = &part[ks][0][0];

// stream-load 4 consecutive k-rows of W_ih1 into named regs
#define SWL(P_, J_) \
    P_##0 = LD4(pih + (size_t)(4*(J_)+0)*GT); \
    P_##1 = LD4(pih + (size_t)(4*(J_)+1)*GT); \
    P_##2 = LD4(pih + (size_t)(4*(J_)+2)*GT); \
    P_##3 = LD4(pih + (size_t)(4*(J_)+3)*GT);

// hh chunk: 4 k (from named wb regs) x 8 rows, sources broadcast from h1s
#define HH(J_, W0_, W1_, W2_, W3_) { \
    const float4 h0_ = LD4(&h1s[0][k1b + 4*(J_)]); \
    const float4 h1_ = LD4(&h1s[1][k1b + 4*(J_)]); \
    const float4 h2_ = LD4(&h1s[2][k1b + 4*(J_)]); \
    const float4 h3_ = LD4(&h1s[3][k1b + 4*(J_)]); \
    const float4 h4_ = LD4(&h1s[4][k1b + 4*(J_)]); \
    const float4 h5_ = LD4(&h1s[5][k1b + 4*(J_)]); \
    const float4 h6_ = LD4(&h1s[6][k1b + 4*(J_)]); \
    const float4 h7_ = LD4(&h1s[7][k1b + 4*(J_)]); \
    FMARC(acc0, h0_.x, W0_) FMARC(acc0, h0_.y, W1_) FMARC(acc0, h0_.z, W2_) FMARC(acc0, h0_.w, W3_) \
    FMARC(acc1, h1_.x, W0_) FMARC(acc1, h1_.y, W1_) FMARC(acc1, h1_.z, W2_) FMARC(acc1, h1_.w, W3_) \
    FMARC(acc2, h2_.x, W0_) FMARC(acc2, h2_.y, W1_) FMARC(acc2, h2_.z, W2_) FMARC(acc2, h2_.w, W3_) \
    FMARC(acc3, h3_.x, W0_) FMARC(acc3, h3_.y, W1_) FMARC(acc3, h3_.z, W2_) FMARC(acc3, h3_.w, W3_) \
    FMARC(acc4, h4_.x, W0_) FMARC(acc4, h4_.y, W1_) FMARC(acc4, h4_.z, W2_) FMARC(acc4, h4_.w, W3_) \
    FMARC(acc5, h5_.x, W0_) FMARC(acc5, h5_.y, W1_) FMARC(acc5, h5_.z, W2_) FMARC(acc5, h5_.w, W3_) \
    FMARC(acc6, h6_.x, W0_) FMARC(acc6, h6_.y, W1_) FMARC(acc6, h6_.z, W2_) FMARC(acc6, h6_.w, W3_) \
    FMARC(acc7, h7_.x, W0_) FMARC(acc7, h7_.y, W1_) FMARC(acc7, h7_.z, W2_) FMARC(acc7, h7_.w, W3_) }

// ih chunk: 4 k (streamed regs P_##0..3) x 8 rows, sources broadcast from obuf[t&1]
#define IH(P_, J_) { \
    const float4 o0_ = LD4(ob + 0*HID + k1b + 4*(J_)); \
    const float4 o1_ = LD4(ob + 1*HID + k1b + 4*(J_)); \
    const float4 o2_ = LD4(ob + 2*HID + k1b + 4*(J_)); \
    const float4 o3_ = LD4(ob + 3*HID + k1b + 4*(J_)); \
    const float4 o4_ = LD4(ob + 4*HID + k1b + 4*(J_)); \
    const float4 o5_ = LD4(ob + 5*HID + k1b + 4*(J_)); \
    const float4 o6_ = LD4(ob + 6*HID + k1b + 4*(J_)); \
    const float4 o7_ = LD4(ob + 7*HID + k1b + 4*(J_)); \
    FMARC(acc0, o0_.x, P_##0) FMARC(acc0, o0_.y, P_##1) FMARC(acc0, o0_.z, P_##2) FMARC(acc0, o0_.w, P_##3) \
    FMARC(acc1, o1_.x, P_##0) FMARC(acc1, o1_.y, P_##1) FMARC(acc1, o1_.z, P_##2) FMARC(acc1, o1_.w, P_##3) \
    FMARC(acc2, o2_.x, P_##0) FMARC(acc2, o2_.y, P_##1) FMARC(acc2, o2_.z, P_##2) FMARC(acc2, o2_.w, P_##3) \
    FMARC(acc3, o3_.x, P_##0) FMARC(acc3, o3_.y, P_##1) FMARC(acc3, o3_.z, P_##2) FMARC(acc3, o3_.w, P_##3) \
    FMARC(acc4, o4_.x, P_##0) FMARC(acc4, o4_.y, P_##1) FMARC(acc4, o4_.z, P_##2) FMARC(acc4, o4_.w, P_##3) \
    FMARC(acc5, o5_.x, P_##0) FMARC(acc5, o5_.y, P_##1) FMARC(acc5, o5_.z, P_##2) FMARC(acc5, o5_.w, P_##3) \
    FMARC(acc6, o6_.x, P_##0) FMARC(acc6, o6_.y, P_##1) FMARC(acc6, o6_.z, P_##2) FMARC(acc6, o6_.w, P_##3) \
    FMARC(acc7, o7_.x, P_##0) FMARC(acc7, o7_.y, P_##1) FMARC(acc7, o7_.z, P_##2) FMARC(acc7, o7_.w, P_##3) }

#define UPD1(R_, C_) { \
    const int ub_ = um << 2; \
    float4 gv_ = LD4(&part[0][R_][ub_]); \
    { const float4 p1_ = LD4(&part[1][R_][ub_]); gv_.x += p1_.x; gv_.y += p1_.y; gv_.z += p1_.z; gv_.w += p1_.w; } \
    { const float4 p2_ = LD4(&part[2][R_][ub_]); gv_.x += p2_.x; gv_.y += p2_.y; gv_.z += p2_.z; gv_.w += p2_.w; } \
    { const float4 p3_ = LD4(&part[3][R_][ub_]); gv_.x += p3_.x; gv_.y += p3_.y; gv_.z += p3_.z; gv_.w += p3_.w; } \
    const float iv_ = sigm(gv_.x), fv_ = sigm(gv_.y), ov_ = sigm(gv_.w); \
    const float gg_ = tanhf(gv_.z); \
    C_ = fmaf(fv_, C_, iv_ * gg_); \
    h1s[R_][um] = ov_ * tanhf(C_); }

    #pragma unroll 1
    for (int t = 0; t < TS; ++t) {
        if (tid < 256 && t + 1 < TS)
            pf = LD4(out0 + (size_t)(row0 + pr) * TS128 + (size_t)(t + 1) * HID + pk4);

        const float* ob = &obuf[t & 1][0][0];
        float4 acc0 = i1, acc1 = i1, acc2 = i1, acc3 = i1;
        float4 acc4 = i1, acc5 = i1, acc6 = i1, acc7 = i1;
        float4 sa0, sa1, sa2, sa3, sb0, sb1, sb2, sb3;

        SWL(sa, 0) SWL(sb, 1)                  // stream chunks 0,1 in flight under hh-part
        HH(0, wb0,  wb1,  wb2,  wb3)
        HH(1, wb4,  wb5,  wb6,  wb7)
        HH(2, wb8,  wb9,  wb10, wb11)
        HH(3, wb12, wb13, wb14, wb15)
        HH(4, wb16, wb17, wb18, wb19)
        HH(5, wb20, wb21, wb22, wb23)
        HH(6, wb24, wb25, wb26, wb27)
        HH(7, wb28, wb29, wb30, wb31)
        IH(sa, 0) SWL(sa, 2)
        IH(sb, 1) SWL(sb, 3)
        IH(sa, 2) SWL(sa, 4)
        IH(sb, 3) SWL(sb, 5)
        IH(sa, 4) SWL(sa, 6)
        IH(sb, 5) SWL(sb, 7)
        IH(sa, 6)
        IH(sb, 7)

        *(float4*)(pp + 0*GT + q4) = acc0;
        *(float4*)(pp + 1*GT + q4) = acc1;
        *(float4*)(pp + 2*GT + q4) = acc2;
        *(float4*)(pp + 3*GT + q4) = acc3;
        *(float4*)(pp + 4*GT + q4) = acc4;
        *(float4*)(pp + 5*GT + q4) = acc5;
        *(float4*)(pp + 6*GT + q4) = acc6;
        *(float4*)(pp + 7*GT + q4) = acc7;
        __syncthreads();

        UPD1(rlo, c_a)
        { const int rhi_ = rlo + 4; UPD1(rhi_, c_b) }
        if (tid < 256 && t + 1 < TS) *(float4*)(&obuf[(t + 1) & 1][pr][pk4]) = pf;
        __syncthreads();
    }

    // ---- FC head: relu(h1 @ W_fc1^T + b_fc1) @ W_fc2^T + b_fc2 ----
    {
        const int rr = tid >> 6, u = tid & 63;   // 8 rows x 64 units = 512 threads
        float acc = b_fc1[u];
        #pragma unroll 8
        for (int k = 0; k < HID; ++k) acc = fmaf(h1s[rr][k], W_fc1[u*HID + k], acc);
        part[0][rr][u] = fmaxf(acc, 0.f);
    }
    __syncthreads();
    if (tid < BB) {
        float acc = b_fc2[0];
        #pragma unroll 8
        for (int u = 0; u < 64; ++u) acc = fmaf(part[0][tid][u], W_fc2[u], acc);
        out[row0 + tid] = acc;
    }
}

extern "C" void kernel_launch(void* const* d_in, const int* in_sizes, int n_in,
                              void* d_out, int out_size, void* d_ws, size_t ws_size,
                              hipStream_t stream)
{
    const float* x     = (const float*)d_in[0];
    const float* W_emb = (const float*)d_in[1];
    const float* b_emb = (const float*)d_in[2];
    const float* W_ih0 = (const float*)d_in[3];
    const float* W_hh0 = (const float*)d_in[4];
    const float* b_ih0 = (const float*)d_in[5];
    const float* b_hh0 = (const float*)d_in[6];
    const float* W_ih1 = (const float*)d_in[7];
    const float* W_hh1 = (const float*)d_in[8];
    const float* b_ih1 = (const float*)d_in[9];
    const float* b_hh1 = (const float*)d_in[10];
    const float* W_fc1 = (const float*)d_in[11];
    const float* b_fc1 = (const float*)d_in[12];
    const float* W_fc2 = (const float*)d_in[13];
    const float* b_fc2 = (const float*)d_in[14];
    float* out = (float*)d_out;

    float* out0;
    hipGetSymbolAddress((void**)&out0, HIP_SYMBOL(g_out0));

    prep_kernel<<<2, 256, 0, stream>>>(W_emb, b_emb, W_ih0, W_hh0, b_ih0, b_hh0,
                                       W_ih1, W_hh1, b_ih1, b_hh1);
    lstm_l0<<<2048 / BB, NT, 0, stream>>>(x, out0);
    lstm_l1<<<2048 / BB, NT, 0, stream>>>(out0, W_fc1, b_fc1, W_fc2, b_fc2, out);
}

// Round 6
// 10777.953 us; speedup vs baseline: 4.8962x; 1.0011x over previous
//
#include <hip/hip_runtime.h>

#define TS    576
#define HID   128
#define GT    512       // 4*HID
#define K0    144       // 15 x (emb-folded) | 128 h0 | 1 zero pad
#define BB    8         // batch rows per block
#define NT    512       // 8 waves -> 2 waves/SIMD, pinned by amdgpu_waves_per_eu(2,2)
#define TS128 (TS*HID)  // 73728

// prepped weights (k-major, gate-interleaved columns jn = unit*4 + gate)
__device__ float g_wt0[K0 * GT];     // [k][col]: k 0..14 x-proj (emb folded), 15..142 h, 143 zero
__device__ float g_b0[GT];
__device__ float g_wih1[HID * GT];   // [k][col]
__device__ float g_whh1[HID * GT];   // [k][col]
__device__ float g_b1[GT];
__device__ float g_out0[2048 * TS * HID];   // 604 MB intermediate: out0[b][t][128]

__global__ void prep_kernel(const float* __restrict__ W_emb, const float* __restrict__ b_emb,
                            const float* __restrict__ W_ih0, const float* __restrict__ W_hh0,
                            const float* __restrict__ b_ih0, const float* __restrict__ b_hh0,
                            const float* __restrict__ W_ih1, const float* __restrict__ W_hh1,
                            const float* __restrict__ b_ih1, const float* __restrict__ b_hh1)
{
    const int jo = blockIdx.x * blockDim.x + threadIdx.x;
    if (jo >= GT) return;
    const int g  = jo >> 7;         // gate 0..3 (i,f,g,o)
    const int u  = jo & 127;        // unit
    const int jn = (u << 2) | g;    // interleaved column

    // L0: fold embedding into x-projection
    for (int i = 0; i < 15; ++i) {
        float s = 0.f;
        for (int c = 0; c < 32; ++c) s = fmaf(W_ih0[jo*32 + c], W_emb[c*15 + i], s);
        g_wt0[i*GT + jn] = s;
    }
    for (int k = 0; k < HID; ++k) g_wt0[(15 + k)*GT + jn] = W_hh0[jo*HID + k];
    g_wt0[143*GT + jn] = 0.f;
    float bb = b_ih0[jo] + b_hh0[jo];
    for (int c = 0; c < 32; ++c) bb = fmaf(W_ih0[jo*32 + c], b_emb[c], bb);
    g_b0[jn] = bb;

    for (int k = 0; k < HID; ++k) g_wih1[k*GT + jn] = W_ih1[jo*HID + k];
    for (int k = 0; k < HID; ++k) g_whh1[k*GT + jn] = W_hh1[jo*HID + k];
    g_b1[jn] = b_ih1[jo] + b_hh1[jo];
}

__device__ __forceinline__ float sigm(float v) { return 1.f / (1.f + __expf(-v)); }

#define LD4(P_) (*(const float4*)(P_))
// macro params must never be named x/y/z/w/a/s
#define FMARC(A_, SV_, W_) \
    A_.x = fmaf(SV_, W_.x, A_.x); A_.y = fmaf(SV_, W_.y, A_.y); \
    A_.z = fmaf(SV_, W_.z, A_.z); A_.w = fmaf(SV_, W_.w, A_.w);

// ============================ Kernel A: layer-0 ============================
// amdgpu_waves_per_eu(2,2): pin RA occupancy target to 2 waves/EU -> 256 VGPR budget.
// (launch_bounds(NT,2) alone let the LDS-derived occupancy (2 blocks/CU = 4 waves/EU)
//  cap the budget at 128 and spill the weight set — round 5 evidence: WRITE_SIZE 611MB.)
__global__ void __attribute__((amdgpu_flat_work_group_size(NT, NT), amdgpu_waves_per_eu(2, 2)))
lstm_l0(const float* __restrict__ x, float* __restrict__ out0)
{
    __shared__ float src0[BB][K0];      // [15 x | 128 h0 | 1 pad]
    __shared__ float part[4][BB][GT];   // 4-way k-split partials (64 KB)

    const int tid  = threadIdx.x;
    const int cg   = tid & 127;
    const int q4   = cg << 2;
    const int ks   = tid >> 7;          // 0..3, wave-uniform
    const int um   = cg;                // update unit
    const int rlo  = tid >> 7;          // update rows rlo and rlo+4
    const int row0 = blockIdx.x * BB;
    const int k0b  = ks * 36;

    // persistent weights: 36 named float4 (144 VGPRs)
    const float* p0 = g_wt0 + (size_t)k0b * GT + q4;
#define DECLA(I_) const float4 wa##I_ = LD4(p0 + (I_)*GT);
    DECLA(0)  DECLA(1)  DECLA(2)  DECLA(3)  DECLA(4)  DECLA(5)
    DECLA(6)  DECLA(7)  DECLA(8)  DECLA(9)  DECLA(10) DECLA(11)
    DECLA(12) DECLA(13) DECLA(14) DECLA(15) DECLA(16) DECLA(17)
    DECLA(18) DECLA(19) DECLA(20) DECLA(21) DECLA(22) DECLA(23)
    DECLA(24) DECLA(25) DECLA(26) DECLA(27) DECLA(28) DECLA(29)
    DECLA(30) DECLA(31) DECLA(32) DECLA(33) DECLA(34) DECLA(35)

    const float4 zz = make_float4(0.f, 0.f, 0.f, 0.f);
    const float4 i0 = (ks == 0) ? LD4(g_b0 + q4) : zz;
    float c_a = 0.f, c_b = 0.f;

    for (int i = tid; i < BB*K0; i += NT) (&src0[0][0])[i] = 0.f;

    const int lr = tid / 15, li = tid - lr * 15;
    const float* xp = x + (size_t)(row0 + (tid < 120 ? lr : 0)) * (TS * 15) + (tid < 120 ? li : 0);

    __syncthreads();
    if (tid < 120) src0[lr][li] = xp[0];
    __syncthreads();

    float* pp = &part[ks][0][0];

#define L0R(R_) { \
    const float* sp_ = &src0[R_][k0b]; \
    const float4 s0_ = LD4(sp_+0),  s1_ = LD4(sp_+4),  s2_ = LD4(sp_+8); \
    const float4 s3_ = LD4(sp_+12), s4_ = LD4(sp_+16), s5_ = LD4(sp_+20); \
    const float4 s6_ = LD4(sp_+24), s7_ = LD4(sp_+28), s8_ = LD4(sp_+32); \
    float4 acc_ = i0; \
    FMARC(acc_, s0_.x, wa0)  FMARC(acc_, s0_.y, wa1)  FMARC(acc_, s0_.z, wa2)  FMARC(acc_, s0_.w, wa3)  \
    FMARC(acc_, s1_.x, wa4)  FMARC(acc_, s1_.y, wa5)  FMARC(acc_, s1_.z, wa6)  FMARC(acc_, s1_.w, wa7)  \
    FMARC(acc_, s2_.x, wa8)  FMARC(acc_, s2_.y, wa9)  FMARC(acc_, s2_.z, wa10) FMARC(acc_, s2_.w, wa11) \
    FMARC(acc_, s3_.x, wa12) FMARC(acc_, s3_.y, wa13) FMARC(acc_, s3_.z, wa14) FMARC(acc_, s3_.w, wa15) \
    FMARC(acc_, s4_.x, wa16) FMARC(acc_, s4_.y, wa17) FMARC(acc_, s4_.z, wa18) FMARC(acc_, s4_.w, wa19) \
    FMARC(acc_, s5_.x, wa20) FMARC(acc_, s5_.y, wa21) FMARC(acc_, s5_.z, wa22) FMARC(acc_, s5_.w, wa23) \
    FMARC(acc_, s6_.x, wa24) FMARC(acc_, s6_.y, wa25) FMARC(acc_, s6_.z, wa26) FMARC(acc_, s6_.w, wa27) \
    FMARC(acc_, s7_.x, wa28) FMARC(acc_, s7_.y, wa29) FMARC(acc_, s7_.z, wa30) FMARC(acc_, s7_.w, wa31) \
    FMARC(acc_, s8_.x, wa32) FMARC(acc_, s8_.y, wa33) FMARC(acc_, s8_.z, wa34) FMARC(acc_, s8_.w, wa35) \
    *(float4*)(pp + (R_)*GT + q4) = acc_; }

#define UPD0(R_, C_) { \
    const int ub_ = um << 2; \
    float4 gv_ = LD4(&part[0][R_][ub_]); \
    { const float4 p1_ = LD4(&part[1][R_][ub_]); gv_.x += p1_.x; gv_.y += p1_.y; gv_.z += p1_.z; gv_.w += p1_.w; } \
    { const float4 p2_ = LD4(&part[2][R_][ub_]); gv_.x += p2_.x; gv_.y += p2_.y; gv_.z += p2_.z; gv_.w += p2_.w; } \
    { const float4 p3_ = LD4(&part[3][R_][ub_]); gv_.x += p3_.x; gv_.y += p3_.y; gv_.z += p3_.z; gv_.w += p3_.w; } \
    const float iv_ = sigm(gv_.x), fv_ = sigm(gv_.y), ov_ = sigm(gv_.w); \
    const float gg_ = tanhf(gv_.z); \
    C_ = fmaf(fv_, C_, iv_ * gg_); \
    const float hv_ = ov_ * tanhf(C_); \
    src0[R_][15 + um] = hv_; \
    out0[(size_t)(row0 + (R_)) * TS128 + (size_t)t * HID + um] = hv_; }

    #pragma unroll 1
    for (int t = 0; t < TS; ++t) {
        float xnext = 0.f;
        if (tid < 120 && t + 1 < TS) xnext = xp[(size_t)(t + 1) * 15];
        L0R(0) L0R(1) L0R(2) L0R(3) L0R(4) L0R(5) L0R(6) L0R(7)
        __syncthreads();
        UPD0(rlo, c_a)
        { const int rhi_ = rlo + 4; UPD0(rhi_, c_b) }
        if (tid < 120 && t + 1 < TS) src0[lr][li] = xnext;
        __syncthreads();
    }
}

// ============================ Kernel C: layer-1 + FC head ============================
__global__ void __attribute__((amdgpu_flat_work_group_size(NT, NT), amdgpu_waves_per_eu(2, 2)))
lstm_l1(const float* __restrict__ out0,
        const float* __restrict__ W_fc1, const float* __restrict__ b_fc1,
        const float* __restrict__ W_fc2, const float* __restrict__ b_fc2,
        float* __restrict__ out)
{
    __shared__ float h1s[BB][HID];       // h1 state              4 KB
    __shared__ float obuf[2][BB][HID];   // out0[t] double buffer 8 KB
    __shared__ float part[4][BB][GT];    // k-split partials     64 KB

    const int tid  = threadIdx.x;
    const int cg   = tid & 127;
    const int q4   = cg << 2;
    const int ks   = tid >> 7;
    const int um   = cg;
    const int rlo  = tid >> 7;
    const int row0 = blockIdx.x * BB;
    const int k1b  = ks * 32;

    // persistent W_hh1 slice: 32 named float4 (128 VGPRs)
    const float* ph = g_whh1 + (size_t)k1b * GT + q4;
#define DECLB(I_) const float4 wb##I_ = LD4(ph + (I_)*GT);
    DECLB(0)  DECLB(1)  DECLB(2)  DECLB(3)  DECLB(4)  DECLB(5)  DECLB(6)  DECLB(7)
    DECLB(8)  DECLB(9)  DECLB(10) DECLB(11) DECLB(12) DECLB(13) DECLB(14) DECLB(15)
    DECLB(16) DECLB(17) DECLB(18) DECLB(19) DECLB(20) DECLB(21) DECLB(22) DECLB(23)
    DECLB(24) DECLB(25) DECLB(26) DECLB(27) DECLB(28) DECLB(29) DECLB(30) DECLB(31)

    const float* pih = g_wih1 + (size_t)k1b * GT + q4;   // streamed per step (L2-resident)

    const float4 zz = make_float4(0.f, 0.f, 0.f, 0.f);
    const float4 i1 = (ks == 0) ? LD4(g_b1 + q4) : zz;
    float c_a = 0.f, c_b = 0.f;

    for (int i = tid; i < BB*HID; i += NT) (&h1s[0][0])[i] = 0.f;

    const int pr = tid >> 5, pk4 = (tid & 31) << 2;   // prefetch role (tid<256)
    float4 pf = zz;
    if (tid < 256) pf = LD4(out0 + (size_t)(row0 + pr) * TS128 + pk4);
    __syncthreads();
    if (tid < 256) *(float4*)(&obuf[0][pr][pk4]) = pf;
    __syncthreads();

    float* pp = &part[ks][0][0];

// stream-load 4 consecutive k-rows of W_ih1 into named regs
#define SWL(P_, J_) \
    P_##0 = LD4(pih + (size_t)(4*(J_)+0)*GT); \
    P_##1 = LD4(pih + (size_t)(4*(J_)+1)*GT); \
    P_##2 = LD4(pih + (size_t)(4*(J_)+2)*GT); \
    P_##3 = LD4(pih + (size_t)(4*(J_)+3)*GT);

// hh 4 k x 4 rows (RB_..RB_+3), accs AA_..AD_ — halved transients vs 8-row form
#define HH4(J_, W0_, W1_, W2_, W3_, RB_, AA_, AB_, AC_, AD_) { \
    const float4 hA_ = LD4(&h1s[(RB_)+0][k1b + 4*(J_)]); \
    const float4 hB_ = LD4(&h1s[(RB_)+1][k1b + 4*(J_)]); \
    const float4 hC_ = LD4(&h1s[(RB_)+2][k1b + 4*(J_)]); \
    const float4 hD_ = LD4(&h1s[(RB_)+3][k1b + 4*(J_)]); \
    FMARC(AA_, hA_.x, W0_) FMARC(AA_, hA_.y, W1_) FMARC(AA_, hA_.z, W2_) FMARC(AA_, hA_.w, W3_) \
    FMARC(AB_, hB_.x, W0_) FMARC(AB_, hB_.y, W1_) FMARC(AB_, hB_.z, W2_) FMARC(AB_, hB_.w, W3_) \
    FMARC(AC_, hC_.x, W0_) FMARC(AC_, hC_.y, W1_) FMARC(AC_, hC_.z, W2_) FMARC(AC_, hC_.w, W3_) \
    FMARC(AD_, hD_.x, W0_) FMARC(AD_, hD_.y, W1_) FMARC(AD_, hD_.z, W2_) FMARC(AD_, hD_.w, W3_) }
#define HH(J_, W0_, W1_, W2_, W3_) \
    HH4(J_, W0_, W1_, W2_, W3_, 0, acc0, acc1, acc2, acc3) \
    HH4(J_, W0_, W1_, W2_, W3_, 4, acc4, acc5, acc6, acc7)

// ih 4 k (streamed regs P_##0..3) x 4 rows from obuf[t&1]
#define IH4(P_, J_, RB_, AA_, AB_, AC_, AD_) { \
    const float4 oA_ = LD4(ob + ((RB_)+0)*HID + k1b + 4*(J_)); \
    const float4 oB_ = LD4(ob + ((RB_)+1)*HID + k1b + 4*(J_)); \
    const float4 oC_ = LD4(ob + ((RB_)+2)*HID + k1b + 4*(J_)); \
    const float4 oD_ = LD4(ob + ((RB_)+3)*HID + k1b + 4*(J_)); \
    FMARC(AA_, oA_.x, P_##0) FMARC(AA_, oA_.y, P_##1) FMARC(AA_, oA_.z, P_##2) FMARC(AA_, oA_.w, P_##3) \
    FMARC(AB_, oB_.x, P_##0) FMARC(AB_, oB_.y, P_##1) FMARC(AB_, oB_.z, P_##2) FMARC(AB_, oB_.w, P_##3) \
    FMARC(AC_, oC_.x, P_##0) FMARC(AC_, oC_.y, P_##1) FMARC(AC_, oC_.z, P_##2) FMARC(AC_, oC_.w, P_##3) \
    FMARC(AD_, oD_.x, P_##0) FMARC(AD_, oD_.y, P_##1) FMARC(AD_, oD_.z, P_##2) FMARC(AD_, oD_.w, P_##3) }
#define IH(P_, J_) \
    IH4(P_, J_, 0, acc0, acc1, acc2, acc3) \
    IH4(P_, J_, 4, acc4, acc5, acc6, acc7)

#define UPD1(R_, C_) { \
    const int ub_ = um << 2; \
    float4 gv_ = LD4(&part[0][R_][ub_]); \
    { const float4 p1_ = LD4(&part[1][R_][ub_]); gv_.x += p1_.x; gv_.y += p1_.y; gv_.z += p1_.z; gv_.w += p1_.w; } \
    { const float4 p2_ = LD4(&part[2][R_][ub_]); gv_.x += p2_.x; gv_.y += p2_.y; gv_.z += p2_.z; gv_.w += p2_.w; } \
    { const float4 p3_ = LD4(&part[3][R_][ub_]); gv_.x += p3_.x; gv_.y += p3_.y; gv_.z += p3_.z; gv_.w += p3_.w; } \
    const float iv_ = sigm(gv_.x), fv_ = sigm(gv_.y), ov_ = sigm(gv_.w); \
    const float gg_ = tanhf(gv_.z); \
    C_ = fmaf(fv_, C_, iv_ * gg_); \
    h1s[R_][um] = ov_ * tanhf(C_); }

    #pragma unroll 1
    for (int t = 0; t < TS; ++t) {
        if (tid < 256 && t + 1 < TS)
            pf = LD4(out0 + (size_t)(row0 + pr) * TS128 + (size_t)(t + 1) * HID + pk4);

        const float* ob = &obuf[t & 1][0][0];
        float4 acc0 = i1, acc1 = i1, acc2 = i1, acc3 = i1;
        float4 acc4 = i1, acc5 = i1, acc6 = i1, acc7 = i1;
        float4 sa0, sa1, sa2, sa3, sb0, sb1, sb2, sb3;

        SWL(sa, 0) SWL(sb, 1)                  // stream chunks 0,1 in flight under hh-part
        HH(0, wb0,  wb1,  wb2,  wb3)
        HH(1, wb4,  wb5,  wb6,  wb7)
        HH(2, wb8,  wb9,  wb10, wb11)
        HH(3, wb12, wb13, wb14, wb15)
        HH(4, wb16, wb17, wb18, wb19)
        HH(5, wb20, wb21, wb22, wb23)
        HH(6, wb24, wb25, wb26, wb27)
        HH(7, wb28, wb29, wb30, wb31)
        IH(sa, 0) SWL(sa, 2)
        IH(sb, 1) SWL(sb, 3)
        IH(sa, 2) SWL(sa, 4)
        IH(sb, 3) SWL(sb, 5)
        IH(sa, 4) SWL(sa, 6)
        IH(sb, 5) SWL(sb, 7)
        IH(sa, 6)
        IH(sb, 7)

        *(float4*)(pp + 0*GT + q4) = acc0;
        *(float4*)(pp + 1*GT + q4) = acc1;
        *(float4*)(pp + 2*GT + q4) = acc2;
        *(float4*)(pp + 3*GT + q4) = acc3;
        *(float4*)(pp + 4*GT + q4) = acc4;
        *(float4*)(pp + 5*GT + q4) = acc5;
        *(float4*)(pp + 6*GT + q4) = acc6;
        *(float4*)(pp + 7*GT + q4) = acc7;
        __syncthreads();

        UPD1(rlo, c_a)
        { const int rhi_ = rlo + 4; UPD1(rhi_, c_b) }
        if (tid < 256 && t + 1 < TS) *(float4*)(&obuf[(t + 1) & 1][pr][pk4]) = pf;
        __syncthreads();
    }

    // ---- FC head: relu(h1 @ W_fc1^T + b_fc1) @ W_fc2^T + b_fc2 ----
    {
        const int rr = tid >> 6, u = tid & 63;   // 8 rows x 64 units = 512 threads
        float acc = b_fc1[u];
        #pragma unroll 8
        for (int k = 0; k < HID; ++k) acc = fmaf(h1s[rr][k], W_fc1[u*HID + k], acc);
        part[0][rr][u] = fmaxf(acc, 0.f);
    }
    __syncthreads();
    if (tid < BB) {
        float acc = b_fc2[0];
        #pragma unroll 8
        for (int u = 0; u < 64; ++u) acc = fmaf(part[0][tid][u], W_fc2[u], acc);
        out[row0 + tid] = acc;
    }
}

extern "C" void kernel_launch(void* const* d_in, const int* in_sizes, int n_in,
                              void* d_out, int out_size, void* d_ws, size_t ws_size,
                              hipStream_t stream)
{
    const float* x     = (const float*)d_in[0];
    const float* W_emb = (const float*)d_in[1];
    const float* b_emb = (const float*)d_in[2];
    const float* W_ih0 = (const float*)d_in[3];
    const float* W_hh0 = (const float*)d_in[4];
    const float* b_ih0 = (const float*)d_in[5];
    const float* b_hh0 = (const float*)d_in[6];
    const float* W_ih1 = (const float*)d_in[7];
    const float* W_hh1 = (const float*)d_in[8];
    const float* b_ih1 = (const float*)d_in[9];
    const float* b_hh1 = (const float*)d_in[10];
    const float* W_fc1 = (const float*)d_in[11];
    const float* b_fc1 = (const float*)d_in[12];
    const float* W_fc2 = (const float*)d_in[13];
    const float* b_fc2 = (const float*)d_in[14];
    float* out = (float*)d_out;

    float* out0;
    hipGetSymbolAddress((void**)&out0, HIP_SYMBOL(g_out0));

    prep_kernel<<<2, 256, 0, stream>>>(W_emb, b_emb, W_ih0, W_hh0, b_ih0, b_hh0,
                                       W_ih1, W_hh1, b_ih1, b_hh1);
    lstm_l0<<<2048 / BB, NT, 0, stream>>>(x, out0);
    lstm_l1<<<2048 / BB, NT, 0, stream>>>(out0, W_fc1, b_fc1, W_fc2, b_fc2, out);
}

// Round 7
// 7994.855 us; speedup vs baseline: 6.6006x; 1.3481x over previous
//
#include <hip/hip_runtime.h>

#define TS    576
#define HID   128
#define GT    512       // 4*HID
#define GTP   640       // padded part stride -> LDS/wg > 80KB -> 1 wg/CU -> 256-VGPR budget
#define K0    144       // 15 x (emb-folded) | 128 h0 | 1 zero pad
#define BB    8         // batch rows per block
#define NT    512       // 8 waves -> 2 waves/SIMD (1 wg/CU via LDS)
#define TS128 (TS*HID)  // 73728

// prepped weights (k-major, gate-interleaved columns jn = unit*4 + gate)
__device__ float g_wt0[K0 * GT];     // [k][col]: k 0..14 x-proj (emb folded), 15..142 h, 143 zero
__device__ float g_b0[GT];
__device__ float g_wih1[HID * GT];   // [k][col]
__device__ float g_whh1[HID * GT];   // [k][col]
__device__ float g_b1[GT];
__device__ float g_out0[2048 * TS * HID];   // 604 MB intermediate: out0[b][t][128]

__global__ void prep_kernel(const float* __restrict__ W_emb, const float* __restrict__ b_emb,
                            const float* __restrict__ W_ih0, const float* __restrict__ W_hh0,
                            const float* __restrict__ b_ih0, const float* __restrict__ b_hh0,
                            const float* __restrict__ W_ih1, const float* __restrict__ W_hh1,
                            const float* __restrict__ b_ih1, const float* __restrict__ b_hh1)
{
    const int jo = blockIdx.x * blockDim.x + threadIdx.x;
    if (jo >= GT) return;
    const int g  = jo >> 7;         // gate 0..3 (i,f,g,o)
    const int u  = jo & 127;        // unit
    const int jn = (u << 2) | g;    // interleaved column

    // L0: fold embedding into x-projection
    for (int i = 0; i < 15; ++i) {
        float s = 0.f;
        for (int c = 0; c < 32; ++c) s = fmaf(W_ih0[jo*32 + c], W_emb[c*15 + i], s);
        g_wt0[i*GT + jn] = s;
    }
    for (int k = 0; k < HID; ++k) g_wt0[(15 + k)*GT + jn] = W_hh0[jo*HID + k];
    g_wt0[143*GT + jn] = 0.f;
    float bb = b_ih0[jo] + b_hh0[jo];
    for (int c = 0; c < 32; ++c) bb = fmaf(W_ih0[jo*32 + c], b_emb[c], bb);
    g_b0[jn] = bb;

    for (int k = 0; k < HID; ++k) g_wih1[k*GT + jn] = W_ih1[jo*HID + k];
    for (int k = 0; k < HID; ++k) g_whh1[k*GT + jn] = W_hh1[jo*HID + k];
    g_b1[jn] = b_ih1[jo] + b_hh1[jo];
}

__device__ __forceinline__ float sigm(float v) { return 1.f / (1.f + __expf(-v)); }

#define LD4(P_) (*(const float4*)(P_))
// macro params must never be named x/y/z/w/a/s
#define FMARC(A_, SV_, W_) \
    A_.x = fmaf(SV_, W_.x, A_.x); A_.y = fmaf(SV_, W_.y, A_.y); \
    A_.z = fmaf(SV_, W_.z, A_.z); A_.w = fmaf(SV_, W_.w, A_.w);

// ============================ Kernel A: layer-0 ============================
// LDS 86.5KB > 81.9KB -> only 1 wg/CU fits -> LDS-derived occupancy 2 waves/EU
// -> RA VGPR budget 256 -> the 144 weight VGPRs stay resident (r5/r6: 76KB LDS
// allowed 2 wg/CU -> budget pinned 128 -> weights rematerialized from L2).
__global__ void __attribute__((amdgpu_flat_work_group_size(NT, NT), amdgpu_waves_per_eu(2, 2)))
lstm_l0(const float* __restrict__ x, float* __restrict__ out0)
{
    __shared__ float src0[BB][K0];      // [15 x | 128 h0 | 1 pad]  4.6 KB
    __shared__ float part[4][BB][GTP];  // 4-way k-split partials    80 KB

    const int tid  = threadIdx.x;
    const int cg   = tid & 127;
    const int q4   = cg << 2;
    const int ks   = tid >> 7;          // 0..3, wave-uniform
    const int um   = cg;                // update unit
    const int rlo  = tid >> 7;          // update rows rlo and rlo+4
    const int row0 = blockIdx.x * BB;
    const int k0b  = ks * 36;

    // persistent weights: 36 named float4 (144 VGPRs)
    const float* p0 = g_wt0 + (size_t)k0b * GT + q4;
#define DECLA(I_) const float4 wa##I_ = LD4(p0 + (I_)*GT);
    DECLA(0)  DECLA(1)  DECLA(2)  DECLA(3)  DECLA(4)  DECLA(5)
    DECLA(6)  DECLA(7)  DECLA(8)  DECLA(9)  DECLA(10) DECLA(11)
    DECLA(12) DECLA(13) DECLA(14) DECLA(15) DECLA(16) DECLA(17)
    DECLA(18) DECLA(19) DECLA(20) DECLA(21) DECLA(22) DECLA(23)
    DECLA(24) DECLA(25) DECLA(26) DECLA(27) DECLA(28) DECLA(29)
    DECLA(30) DECLA(31) DECLA(32) DECLA(33) DECLA(34) DECLA(35)

    const float4 zz = make_float4(0.f, 0.f, 0.f, 0.f);
    const float4 i0 = (ks == 0) ? LD4(g_b0 + q4) : zz;
    float c_a = 0.f, c_b = 0.f;

    for (int i = tid; i < BB*K0; i += NT) (&src0[0][0])[i] = 0.f;

    const int lr = tid / 15, li = tid - lr * 15;
    const float* xp = x + (size_t)(row0 + (tid < 120 ? lr : 0)) * (TS * 15) + (tid < 120 ? li : 0);

    __syncthreads();
    if (tid < 120) src0[lr][li] = xp[0];
    __syncthreads();

    float* pp = &part[ks][0][0];

#define L0R(R_) { \
    const float* sp_ = &src0[R_][k0b]; \
    const float4 s0_ = LD4(sp_+0),  s1_ = LD4(sp_+4),  s2_ = LD4(sp_+8); \
    const float4 s3_ = LD4(sp_+12), s4_ = LD4(sp_+16), s5_ = LD4(sp_+20); \
    const float4 s6_ = LD4(sp_+24), s7_ = LD4(sp_+28), s8_ = LD4(sp_+32); \
    float4 acc_ = i0; \
    FMARC(acc_, s0_.x, wa0)  FMARC(acc_, s0_.y, wa1)  FMARC(acc_, s0_.z, wa2)  FMARC(acc_, s0_.w, wa3)  \
    FMARC(acc_, s1_.x, wa4)  FMARC(acc_, s1_.y, wa5)  FMARC(acc_, s1_.z, wa6)  FMARC(acc_, s1_.w, wa7)  \
    FMARC(acc_, s2_.x, wa8)  FMARC(acc_, s2_.y, wa9)  FMARC(acc_, s2_.z, wa10) FMARC(acc_, s2_.w, wa11) \
    FMARC(acc_, s3_.x, wa12) FMARC(acc_, s3_.y, wa13) FMARC(acc_, s3_.z, wa14) FMARC(acc_, s3_.w, wa15) \
    FMARC(acc_, s4_.x, wa16) FMARC(acc_, s4_.y, wa17) FMARC(acc_, s4_.z, wa18) FMARC(acc_, s4_.w, wa19) \
    FMARC(acc_, s5_.x, wa20) FMARC(acc_, s5_.y, wa21) FMARC(acc_, s5_.z, wa22) FMARC(acc_, s5_.w, wa23) \
    FMARC(acc_, s6_.x, wa24) FMARC(acc_, s6_.y, wa25) FMARC(acc_, s6_.z, wa26) FMARC(acc_, s6_.w, wa27) \
    FMARC(acc_, s7_.x, wa28) FMARC(acc_, s7_.y, wa29) FMARC(acc_, s7_.z, wa30) FMARC(acc_, s7_.w, wa31) \
    FMARC(acc_, s8_.x, wa32) FMARC(acc_, s8_.y, wa33) FMARC(acc_, s8_.z, wa34) FMARC(acc_, s8_.w, wa35) \
    *(float4*)(pp + (R_)*GTP + q4) = acc_; }

#define UPD0(R_, C_) { \
    const int ub_ = um << 2; \
    float4 gv_ = LD4(&part[0][R_][ub_]); \
    { const float4 p1_ = LD4(&part[1][R_][ub_]); gv_.x += p1_.x; gv_.y += p1_.y; gv_.z += p1_.z; gv_.w += p1_.w; } \
    { const float4 p2_ = LD4(&part[2][R_][ub_]); gv_.x += p2_.x; gv_.y += p2_.y; gv_.z += p2_.z; gv_.w += p2_.w; } \
    { const float4 p3_ = LD4(&part[3][R_][ub_]); gv_.x += p3_.x; gv_.y += p3_.y; gv_.z += p3_.z; gv_.w += p3_.w; } \
    const float iv_ = sigm(gv_.x), fv_ = sigm(gv_.y), ov_ = sigm(gv_.w); \
    const float gg_ = tanhf(gv_.z); \
    C_ = fmaf(fv_, C_, iv_ * gg_); \
    const float hv_ = ov_ * tanhf(C_); \
    src0[R_][15 + um] = hv_; \
    out0[(size_t)(row0 + (R_)) * TS128 + (size_t)t * HID + um] = hv_; }

    #pragma unroll 1
    for (int t = 0; t < TS; ++t) {
        float xnext = 0.f;
        if (tid < 120 && t + 1 < TS) xnext = xp[(size_t)(t + 1) * 15];
        L0R(0) L0R(1) L0R(2) L0R(3) L0R(4) L0R(5) L0R(6) L0R(7)
        __syncthreads();
        UPD0(rlo, c_a)
        { const int rhi_ = rlo + 4; UPD0(rhi_, c_b) }
        if (tid < 120 && t + 1 < TS) src0[lr][li] = xnext;
        __syncthreads();
    }
}

// ============================ Kernel C: layer-1 + FC head ============================
// LDS 94.2KB -> 1 wg/CU -> 256-VGPR budget (same mechanism as lstm_l0).
__global__ void __attribute__((amdgpu_flat_work_group_size(NT, NT), amdgpu_waves_per_eu(2, 2)))
lstm_l1(const float* __restrict__ out0,
        const float* __restrict__ W_fc1, const float* __restrict__ b_fc1,
        const float* __restrict__ W_fc2, const float* __restrict__ b_fc2,
        float* __restrict__ out)
{
    __shared__ float h1s[BB][HID];       // h1 state              4 KB
    __shared__ float obuf[2][BB][HID];   // out0[t] double buffer 8 KB
    __shared__ float part[4][BB][GTP];   // k-split partials     80 KB

    const int tid  = threadIdx.x;
    const int cg   = tid & 127;
    const int q4   = cg << 2;
    const int ks   = tid >> 7;
    const int um   = cg;
    const int rlo  = tid >> 7;
    const int row0 = blockIdx.x * BB;
    const int k1b  = ks * 32;

    // persistent W_hh1 slice: 32 named float4 (128 VGPRs)
    const float* ph = g_whh1 + (size_t)k1b * GT + q4;
#define DECLB(I_) const float4 wb##I_ = LD4(ph + (I_)*GT);
    DECLB(0)  DECLB(1)  DECLB(2)  DECLB(3)  DECLB(4)  DECLB(5)  DECLB(6)  DECLB(7)
    DECLB(8)  DECLB(9)  DECLB(10) DECLB(11) DECLB(12) DECLB(13) DECLB(14) DECLB(15)
    DECLB(16) DECLB(17) DECLB(18) DECLB(19) DECLB(20) DECLB(21) DECLB(22) DECLB(23)
    DECLB(24) DECLB(25) DECLB(26) DECLB(27) DECLB(28) DECLB(29) DECLB(30) DECLB(31)

    const float* pih = g_wih1 + (size_t)k1b * GT + q4;   // streamed per step (L2-resident)

    const float4 zz = make_float4(0.f, 0.f, 0.f, 0.f);
    const float4 i1 = (ks == 0) ? LD4(g_b1 + q4) : zz;
    float c_a = 0.f, c_b = 0.f;

    for (int i = tid; i < BB*HID; i += NT) (&h1s[0][0])[i] = 0.f;

    const int pr = tid >> 5, pk4 = (tid & 31) << 2;   // prefetch role (tid<256)
    float4 pf = zz;
    if (tid < 256) pf = LD4(out0 + (size_t)(row0 + pr) * TS128 + pk4);
    __syncthreads();
    if (tid < 256) *(float4*)(&obuf[0][pr][pk4]) = pf;
    __syncthreads();

    float* pp = &part[ks][0][0];

// stream-load 4 consecutive k-rows of W_ih1 into named regs
#define SWL(P_, J_) \
    P_##0 = LD4(pih + (size_t)(4*(J_)+0)*GT); \
    P_##1 = LD4(pih + (size_t)(4*(J_)+1)*GT); \
    P_##2 = LD4(pih + (size_t)(4*(J_)+2)*GT); \
    P_##3 = LD4(pih + (size_t)(4*(J_)+3)*GT);

// hh 4 k x 4 rows (RB_..RB_+3), accs AA_..AD_
#define HH4(J_, W0_, W1_, W2_, W3_, RB_, AA_, AB_, AC_, AD_) { \
    const float4 hA_ = LD4(&h1s[(RB_)+0][k1b + 4*(J_)]); \
    const float4 hB_ = LD4(&h1s[(RB_)+1][k1b + 4*(J_)]); \
    const float4 hC_ = LD4(&h1s[(RB_)+2][k1b + 4*(J_)]); \
    const float4 hD_ = LD4(&h1s[(RB_)+3][k1b + 4*(J_)]); \
    FMARC(AA_, hA_.x, W0_) FMARC(AA_, hA_.y, W1_) FMARC(AA_, hA_.z, W2_) FMARC(AA_, hA_.w, W3_) \
    FMARC(AB_, hB_.x, W0_) FMARC(AB_, hB_.y, W1_) FMARC(AB_, hB_.z, W2_) FMARC(AB_, hB_.w, W3_) \
    FMARC(AC_, hC_.x, W0_) FMARC(AC_, hC_.y, W1_) FMARC(AC_, hC_.z, W2_) FMARC(AC_, hC_.w, W3_) \
    FMARC(AD_, hD_.x, W0_) FMARC(AD_, hD_.y, W1_) FMARC(AD_, hD_.z, W2_) FMARC(AD_, hD_.w, W3_) }
#define HH(J_, W0_, W1_, W2_, W3_) \
    HH4(J_, W0_, W1_, W2_, W3_, 0, acc0, acc1, acc2, acc3) \
    HH4(J_, W0_, W1_, W2_, W3_, 4, acc4, acc5, acc6, acc7)

// ih 4 k (streamed regs P_##0..3) x 4 rows from obuf[t&1]
#define IH4(P_, J_, RB_, AA_, AB_, AC_, AD_) { \
    const float4 oA_ = LD4(ob + ((RB_)+0)*HID + k1b + 4*(J_)); \
    const float4 oB_ = LD4(ob + ((RB_)+1)*HID + k1b + 4*(J_)); \
    const float4 oC_ = LD4(ob + ((RB_)+2)*HID + k1b + 4*(J_)); \
    const float4 oD_ = LD4(ob + ((RB_)+3)*HID + k1b + 4*(J_)); \
    FMARC(AA_, oA_.x, P_##0) FMARC(AA_, oA_.y, P_##1) FMARC(AA_, oA_.z, P_##2) FMARC(AA_, oA_.w, P_##3) \
    FMARC(AB_, oB_.x, P_##0) FMARC(AB_, oB_.y, P_##1) FMARC(AB_, oB_.z, P_##2) FMARC(AB_, oB_.w, P_##3) \
    FMARC(AC_, oC_.x, P_##0) FMARC(AC_, oC_.y, P_##1) FMARC(AC_, oC_.z, P_##2) FMARC(AC_, oC_.w, P_##3) \
    FMARC(AD_, oD_.x, P_##0) FMARC(AD_, oD_.y, P_##1) FMARC(AD_, oD_.z, P_##2) FMARC(AD_, oD_.w, P_##3) }
#define IH(P_, J_) \
    IH4(P_, J_, 0, acc0, acc1, acc2, acc3) \
    IH4(P_, J_, 4, acc4, acc5, acc6, acc7)

#define UPD1(R_, C_) { \
    const int ub_ = um << 2; \
    float4 gv_ = LD4(&part[0][R_][ub_]); \
    { const float4 p1_ = LD4(&part[1][R_][ub_]); gv_.x += p1_.x; gv_.y += p1_.y; gv_.z += p1_.z; gv_.w += p1_.w; } \
    { const float4 p2_ = LD4(&part[2][R_][ub_]); gv_.x += p2_.x; gv_.y += p2_.y; gv_.z += p2_.z; gv_.w += p2_.w; } \
    { const float4 p3_ = LD4(&part[3][R_][ub_]); gv_.x += p3_.x; gv_.y += p3_.y; gv_.z += p3_.z; gv_.w += p3_.w; } \
    const float iv_ = sigm(gv_.x), fv_ = sigm(gv_.y), ov_ = sigm(gv_.w); \
    const float gg_ = tanhf(gv_.z); \
    C_ = fmaf(fv_, C_, iv_ * gg_); \
    h1s[R_][um] = ov_ * tanhf(C_); }

    #pragma unroll 1
    for (int t = 0; t < TS; ++t) {
        if (tid < 256 && t + 1 < TS)
            pf = LD4(out0 + (size_t)(row0 + pr) * TS128 + (size_t)(t + 1) * HID + pk4);

        const float* ob = &obuf[t & 1][0][0];
        float4 acc0 = i1, acc1 = i1, acc2 = i1, acc3 = i1;
        float4 acc4 = i1, acc5 = i1, acc6 = i1, acc7 = i1;
        float4 sa0, sa1, sa2, sa3, sb0, sb1, sb2, sb3;

        SWL(sa, 0) SWL(sb, 1)                  // stream chunks 0,1 in flight under hh-part
        HH(0, wb0,  wb1,  wb2,  wb3)
        HH(1, wb4,  wb5,  wb6,  wb7)
        HH(2, wb8,  wb9,  wb10, wb11)
        HH(3, wb12, wb13, wb14, wb15)
        HH(4, wb16, wb17, wb18, wb19)
        HH(5, wb20, wb21, wb22, wb23)
        HH(6, wb24, wb25, wb26, wb27)
        HH(7, wb28, wb29, wb30, wb31)
        IH(sa, 0) SWL(sa, 2)
        IH(sb, 1) SWL(sb, 3)
        IH(sa, 2) SWL(sa, 4)
        IH(sb, 3) SWL(sb, 5)
        IH(sa, 4) SWL(sa, 6)
        IH(sb, 5) SWL(sb, 7)
        IH(sa, 6)
        IH(sb, 7)

        *(float4*)(pp + 0*GTP + q4) = acc0;
        *(float4*)(pp + 1*GTP + q4) = acc1;
        *(float4*)(pp + 2*GTP + q4) = acc2;
        *(float4*)(pp + 3*GTP + q4) = acc3;
        *(float4*)(pp + 4*GTP + q4) = acc4;
        *(float4*)(pp + 5*GTP + q4) = acc5;
        *(float4*)(pp + 6*GTP + q4) = acc6;
        *(float4*)(pp + 7*GTP + q4) = acc7;
        __syncthreads();

        UPD1(rlo, c_a)
        { const int rhi_ = rlo + 4; UPD1(rhi_, c_b) }
        if (tid < 256 && t + 1 < TS) *(float4*)(&obuf[(t + 1) & 1][pr][pk4]) = pf;
        __syncthreads();
    }

    // ---- FC head: relu(h1 @ W_fc1^T + b_fc1) @ W_fc2^T + b_fc2 ----
    {
        const int rr = tid >> 6, u = tid & 63;   // 8 rows x 64 units = 512 threads
        float acc = b_fc1[u];
        #pragma unroll 8
        for (int k = 0; k < HID; ++k) acc = fmaf(h1s[rr][k], W_fc1[u*HID + k], acc);
        part[0][rr][u] = fmaxf(acc, 0.f);
    }
    __syncthreads();
    if (tid < BB) {
        float acc = b_fc2[0];
        #pragma unroll 8
        for (int u = 0; u < 64; ++u) acc = fmaf(part[0][tid][u], W_fc2[u], acc);
        out[row0 + tid] = acc;
    }
}

extern "C" void kernel_launch(void* const* d_in, const int* in_sizes, int n_in,
                              void* d_out, int out_size, void* d_ws, size_t ws_size,
                              hipStream_t stream)
{
    const float* x     = (const float*)d_in[0];
    const float* W_emb = (const float*)d_in[1];
    const float* b_emb = (const float*)d_in[2];
    const float* W_ih0 = (const float*)d_in[3];
    const float* W_hh0 = (const float*)d_in[4];
    const float* b_ih0 = (const float*)d_in[5];
    const float* b_hh0 = (const float*)d_in[6];
    const float* W_ih1 = (const float*)d_in[7];
    const float* W_hh1 = (const float*)d_in[8];
    const float* b_ih1 = (const float*)d_in[9];
    const float* b_hh1 = (const float*)d_in[10];
    const float* W_fc1 = (const float*)d_in[11];
    const float* b_fc1 = (const float*)d_in[12];
    const float* W_fc2 = (const float*)d_in[13];
    const float* b_fc2 = (const float*)d_in[14];
    float* out = (float*)d_out;

    float* out0;
    hipGetSymbolAddress((void**)&out0, HIP_SYMBOL(g_out0));

    prep_kernel<<<2, 256, 0, stream>>>(W_emb, b_emb, W_ih0, W_hh0, b_ih0, b_hh0,
                                       W_ih1, W_hh1, b_ih1, b_hh1);
    lstm_l0<<<2048 / BB, NT, 0, stream>>>(x, out0);
    lstm_l1<<<2048 / BB, NT, 0, stream>>>(out0, W_fc1, b_fc1, W_fc2, b_fc2, out);
}